// Round 4
// baseline (413.928 us; speedup 1.0000x reference)
//
#include <hip/hip_runtime.h>
#include <math.h>

// B=64, N=512, T=6, H=4, E=256, hd=64 ; BN=32768 chunks
#define TT 6
#define HH 4
#define EE 256
#define NTHREADS 256

typedef __attribute__((ext_vector_type(8))) short bf16x8;
typedef __attribute__((ext_vector_type(4))) float f32x4;

__device__ __forceinline__ unsigned short f2b(float f) {
    union { float f; unsigned u; } v; v.f = f;
    unsigned u = v.u + 0x7fffu + ((v.u >> 16) & 1u);
    return (unsigned short)(u >> 16);
}
__device__ __forceinline__ float b2f(unsigned short s) {
    union { unsigned u; float f; } v; v.u = ((unsigned)s) << 16;
    return v.f;
}

// ---------------- workspace layout (bytes) ----------------
//   swt  [16][256] bf16   @ 0        (rows 4..15 zero)
//   sb   [4]  f32         @ 8192
//   wvb  [256][256] bf16  @ 8208
//   owb  [256][256] bf16  @ 139280
//   w1b  [128][256] bf16  @ 270352
//   vld  [32768] f32      @ 335888
//   xbar [slice][1024]bf16@ 466960
#define SWT_OFF 0
#define SB_OFF  8192
#define WVB_OFF 8208
#define OWB_OFF 139280
#define W1B_OFF 270352
#define VLD_OFF 335888
#define XB_OFF  466960

// ---- setup (one kernel, no cross-block deps):
//   all blocks: grid-stride bf16 casts of Wv / out_w / w1
//   blocks 0..3: compute q-slice for head n, fold into swt[n], sb[n]
//   block 4: zero swt rows 4..15
__global__ void setup_all(const float* __restrict__ query,
                          const float* __restrict__ in_proj_w,
                          const float* __restrict__ in_proj_b,
                          const float* __restrict__ out_w,
                          const float* __restrict__ w1,
                          unsigned char* __restrict__ ws)
{
    unsigned short* swt = (unsigned short*)(ws + SWT_OFF);
    float*          sb  = (float*)(ws + SB_OFF);
    unsigned short* wvb = (unsigned short*)(ws + WVB_OFF);
    unsigned short* owb = (unsigned short*)(ws + OWB_OFF);
    unsigned short* w1b = (unsigned short*)(ws + W1B_OFF);

    const int tid = threadIdx.x;
    const int gidx = blockIdx.x * NTHREADS + tid;
    const int gstride = gridDim.x * NTHREADS;

    for (int i = gidx; i < 65536; i += gstride) wvb[i] = f2b(in_proj_w[512 * 256 + i]);
    for (int i = gidx; i < 65536; i += gstride) owb[i] = f2b(out_w[i]);
    for (int i = gidx; i < 32768; i += gstride) w1b[i] = f2b(w1[i]);

    if (blockIdx.x < HH) {
        const int n = blockIdx.x;
        __shared__ float qld[64];
        // q[n*64+d] = query . Wq[n*64+d,:] + bq  (4 threads per row)
        {
            int d = tid >> 2, qt = tid & 3;
            const float* wr = in_proj_w + (size_t)(n * 64 + d) * EE + qt * 64;
            const float* qr = query + qt * 64;
            float part = 0.f;
            for (int e = 0; e < 64; e += 4) {
                float4 w = *(const float4*)(wr + e);
                float4 q = *(const float4*)(qr + e);
                part += w.x * q.x + w.y * q.y + w.z * q.z + w.w * q.w;
            }
            part += __shfl_xor(part, 1, 64);
            part += __shfl_xor(part, 2, 64);
            if (qt == 0) qld[d] = part + in_proj_b[n * 64 + d];
        }
        __syncthreads();
        // swt[n][k] = sum_d qld[d] * Wk[n*64+d][k]
        {
            float a = 0.f;
            for (int d = 0; d < 64; ++d)
                a += qld[d] * in_proj_w[(size_t)(EE + n * 64 + d) * EE + tid];
            swt[n * EE + tid] = f2b(a);
        }
        if (tid == 0) {
            float a = 0.f;
            for (int d = 0; d < 64; ++d) a += qld[d] * in_proj_b[EE + n * 64 + d];
            sb[n] = a;
        }
    } else if (blockIdx.x == HH) {
        for (int i = HH * EE + tid; i < 16 * EE; i += NTHREADS) swt[i] = 0;
    }
}

// ================= K1: scores -> softmax -> xbar (8 chunks/block) =================
__global__ __launch_bounds__(NTHREADS, 5)
void k1_attn(const float* __restrict__ x,
             const int* __restrict__ mask,
             unsigned char* __restrict__ ws,
             int s0)
{
    __shared__ __align__(16) unsigned short xs[48 * 260];   // 24960 B
    __shared__ float scf[48 * 5];
    __shared__ float aw4[8 * TT * 4];
    __shared__ int   mbuf[48];

    const unsigned short* swt = (const unsigned short*)(ws + SWT_OFF);
    const float*          sb  = (const float*)(ws + SB_OFF);
    float*                vld = (float*)(ws + VLD_OFF);
    unsigned*             xbg = (unsigned*)(ws + XB_OFF);

    const int tid = threadIdx.x;
    const int wv  = tid >> 6;
    const int ln  = tid & 63;
    const int qd  = ln >> 4;
    const int nl  = ln & 15;
    const int c0  = s0 + blockIdx.x * 8;      // global chunk base
    const int r0  = blockIdx.x * 8;           // slice-local chunk base

    if (tid < 48) mbuf[tid] = mask[(size_t)c0 * TT + tid];
    // load x -> xs bf16 (48 rows x 256)
    {
        const float* xp = x + (size_t)c0 * (TT * EE);
#pragma unroll
        for (int i = 0; i < 12; ++i) {
            int f = i * 1024 + tid * 4;
            float4 v = *(const float4*)(xp + f);
            int r = f >> 8, e = f & 255;
            union { unsigned short u[4]; uint2 v2; } t2;
            t2.u[0] = f2b(v.x); t2.u[1] = f2b(v.y);
            t2.u[2] = f2b(v.z); t2.u[3] = f2b(v.w);
            *(uint2*)(xs + r * 260 + e) = t2.v2;
        }
    }
    __syncthreads();
    // scores MFMA: 3 M-tiles of 16 rows (waves 0..2)
    if (wv < 3) {
        const int mt = wv;
        f32x4 acc = {0.f, 0.f, 0.f, 0.f};
        for (int kb = 0; kb < EE; kb += 32) {
            bf16x8 a = *(const bf16x8*)(xs + (mt * 16 + nl) * 260 + kb + qd * 8);
            bf16x8 b = *(const bf16x8*)(swt + nl * EE + kb + qd * 8);
            acc = __builtin_amdgcn_mfma_f32_16x16x32_bf16(a, b, acc, 0, 0, 0);
        }
        if (nl < HH) {
#pragma unroll
            for (int i = 0; i < 4; ++i)
                scf[(mt * 16 + qd * 4 + i) * 5 + nl] = acc[i];
        }
    }
    __syncthreads();
    // softmax (tid<32: (g,h))
    if (tid < 32) {
        int g = tid >> 2, h = tid & 3;
        const int* mrow = mbuf + g * TT;
        float sbh = sb[h];
        float vs[TT]; float m = -1e30f;
#pragma unroll
        for (int t = 0; t < TT; ++t) {
            float s = scf[(g * TT + t) * 5 + h] * 0.125f + sbh;
            s = mrow[t] ? s : -1e9f;
            vs[t] = s; m = fmaxf(m, s);
        }
        float sum = 0.f;
#pragma unroll
        for (int t = 0; t < TT; ++t) { float e = __expf(vs[t] - m); vs[t] = e; sum += e; }
        float inv = 1.f / sum;
#pragma unroll
        for (int t = 0; t < TT; ++t) aw4[(g * TT + t) * 4 + h] = vs[t] * inv;
        if (h == 0) {
            int vvv = 0;
#pragma unroll
            for (int t = 0; t < TT; ++t) vvv |= mrow[t];
            vld[c0 + g] = vvv ? 1.f : 0.f;
        }
    }
    __syncthreads();
    // xbar -> global (bf16 packed pairs); thread: 2 e-cols x 4 chunks
    {
        const int e  = (tid & 127) * 2;
        const int g0 = (tid >> 7) * 4;
        for (int gi = 0; gi < 4; ++gi) {
            int g = g0 + gi;
            float a0[HH] = {0.f, 0.f, 0.f, 0.f};
            float a1[HH] = {0.f, 0.f, 0.f, 0.f};
#pragma unroll
            for (int t = 0; t < TT; ++t) {
                unsigned xp2 = *(const unsigned*)(xs + (g * TT + t) * 260 + e);
                float x0 = b2f((unsigned short)(xp2 & 0xffffu));
                float x1 = b2f((unsigned short)(xp2 >> 16));
                float4 a = *(const float4*)(aw4 + (g * TT + t) * 4);
                a0[0] += a.x * x0; a0[1] += a.y * x0; a0[2] += a.z * x0; a0[3] += a.w * x0;
                a1[0] += a.x * x1; a1[1] += a.y * x1; a1[2] += a.z * x1; a1[3] += a.w * x1;
            }
            size_t row = (size_t)(r0 + g) * 512;   // unsigned units (1024 shorts)
#pragma unroll
            for (int h = 0; h < HH; ++h) {
                unsigned pk = (unsigned)f2b(a0[h]) | ((unsigned)f2b(a1[h]) << 16);
                xbg[row + h * 128 + (e >> 1)] = pk;
            }
        }
    }
}

// ================= K2: Wv -> out_proj -> LN -> MLP -> logits =================
// One wave = 16 chunks. ZERO barriers: each wave owns a private LDS tile;
// B1 writes it (C-layout), B2 re-reads it (A-layout) in the same wave
// (lgkmcnt ordering); LN + final dot are in-register via C-layout row groups.
__global__ __launch_bounds__(NTHREADS, 3)
void k2_head(const float* __restrict__ in_proj_b,
             const float* __restrict__ out_b,
             const float* __restrict__ ln_g,
             const float* __restrict__ ln_b,
             const float* __restrict__ b1,
             const float* __restrict__ w2,
             const float* __restrict__ b2,
             const unsigned char* __restrict__ ws,
             int s0,
             float* __restrict__ out)
{
    __shared__ __align__(16) unsigned short ybuf[4][16 * 264];   // 33792 B

    const unsigned short* xbg = (const unsigned short*)(ws + XB_OFF);
    const unsigned short* wvb = (const unsigned short*)(ws + WVB_OFF);
    const unsigned short* owb = (const unsigned short*)(ws + OWB_OFF);
    const unsigned short* w1b = (const unsigned short*)(ws + W1B_OFF);
    const float*          vld = (const float*)(ws + VLD_OFF);

    const int tid = threadIdx.x;
    const int wv  = tid >> 6;
    const int ln  = tid & 63;
    const int qd  = ln >> 4;
    const int nl  = ln & 15;
    const int lr0 = blockIdx.x * 64 + wv * 16;   // slice-local chunk base of this wave
    const int gc0 = s0 + lr0;                    // global chunk base
    unsigned short* yw = ybuf[wv];

    // ---- B1: ypre = blockdiag(Wv) @ xbar + bv  -> yw (bf16, C-layout rows)
    {
        f32x4 acc[16];
#pragma unroll
        for (int u = 0; u < 16; ++u) acc[u] = (f32x4){0.f, 0.f, 0.f, 0.f};
        for (int h = 0; h < HH; ++h) {
            for (int kb = 0; kb < 8; ++kb) {
                bf16x8 a = *(const bf16x8*)(xbg + (size_t)(lr0 + nl) * 1024 + h * 256 + kb * 32 + qd * 8);
#pragma unroll
                for (int nt = 0; nt < 4; ++nt) {
                    int j = h * 64 + nt * 16 + nl;
                    bf16x8 b = *(const bf16x8*)(wvb + (size_t)j * EE + kb * 32 + qd * 8);
                    acc[h * 4 + nt] = __builtin_amdgcn_mfma_f32_16x16x32_bf16(a, b, acc[h * 4 + nt], 0, 0, 0);
                }
            }
        }
#pragma unroll
        for (int u = 0; u < 16; ++u) {
            int j = u * 16 + nl;
            float bv = in_proj_b[2 * EE + j];
#pragma unroll
            for (int i = 0; i < 4; ++i)
                yw[(qd * 4 + i) * 264 + j] = f2b(acc[u][i] + bv);
        }
    }

    // ---- B2: outv = out_w @ ypre + out_b  (A from yw, same wave)
    float val[16][4];
    {
        f32x4 acc[16];
#pragma unroll
        for (int u = 0; u < 16; ++u) acc[u] = (f32x4){0.f, 0.f, 0.f, 0.f};
        for (int kb = 0; kb < 8; ++kb) {
            bf16x8 a = *(const bf16x8*)(yw + nl * 264 + kb * 32 + qd * 8);
#pragma unroll
            for (int u = 0; u < 16; ++u) {
                bf16x8 b = *(const bf16x8*)(owb + (size_t)(u * 16 + nl) * EE + kb * 32 + qd * 8);
                acc[u] = __builtin_amdgcn_mfma_f32_16x16x32_bf16(a, b, acc[u], 0, 0, 0);
            }
        }
#pragma unroll
        for (int u = 0; u < 16; ++u) {
            float ob = out_b[u * 16 + nl];
#pragma unroll
            for (int i = 0; i < 4; ++i) val[u][i] = acc[u][i] + ob;
        }
    }

    // ---- LN in-register: row r = qd*4+i lives in this qd group's 16 nl-lanes
    {
        float s[4] = {0.f, 0.f, 0.f, 0.f}, ss[4] = {0.f, 0.f, 0.f, 0.f};
#pragma unroll
        for (int u = 0; u < 16; ++u)
#pragma unroll
            for (int i = 0; i < 4; ++i) { s[i] += val[u][i]; ss[i] += val[u][i] * val[u][i]; }
#pragma unroll
        for (int d = 1; d <= 8; d <<= 1) {
#pragma unroll
            for (int i = 0; i < 4; ++i) {
                s[i]  += __shfl_xor(s[i], d, 64);
                ss[i] += __shfl_xor(ss[i], d, 64);
            }
        }
        float mu[4], rstd[4];
#pragma unroll
        for (int i = 0; i < 4; ++i) {
            mu[i] = s[i] * (1.f / EE);
            float var = ss[i] * (1.f / EE) - mu[i] * mu[i];
            rstd[i] = rsqrtf(var + 1e-5f);
        }
#pragma unroll
        for (int u = 0; u < 16; ++u) {
            int j = u * 16 + nl;
            float gg = ln_g[j], bb = ln_b[j];
#pragma unroll
            for (int i = 0; i < 4; ++i) {
                float o = (val[u][i] - mu[i]) * rstd[i] * gg + bb;
                yw[(qd * 4 + i) * 264 + j] = f2b(o);   // lnb over yw (same wave)
            }
        }
    }

    // ---- D: h = gelu(ln @ w1^T + b1)   (A from yw, same wave)
    float ge[8][4];
    {
        f32x4 acc[8];
#pragma unroll
        for (int u = 0; u < 8; ++u) acc[u] = (f32x4){0.f, 0.f, 0.f, 0.f};
        for (int kb = 0; kb < 8; ++kb) {
            bf16x8 a = *(const bf16x8*)(yw + nl * 264 + kb * 32 + qd * 8);
#pragma unroll
            for (int u = 0; u < 8; ++u) {
                bf16x8 b = *(const bf16x8*)(w1b + (size_t)(u * 16 + nl) * EE + kb * 32 + qd * 8);
                acc[u] = __builtin_amdgcn_mfma_f32_16x16x32_bf16(a, b, acc[u], 0, 0, 0);
            }
        }
#pragma unroll
        for (int u = 0; u < 8; ++u) {
            float bj = b1[u * 16 + nl];
#pragma unroll
            for (int i = 0; i < 4; ++i) {
                float sv = acc[u][i] + bj;
                ge[u][i] = 0.5f * sv * (1.0f + erff(sv * 0.70710678118654752f));
            }
        }
    }

    // ---- E: logits = h @ w2 + b2, masked (in-register)
    {
        float w2v[8];
#pragma unroll
        for (int u = 0; u < 8; ++u) w2v[u] = w2[u * 16 + nl];
        float part[4] = {0.f, 0.f, 0.f, 0.f};
#pragma unroll
        for (int u = 0; u < 8; ++u)
#pragma unroll
            for (int i = 0; i < 4; ++i) part[i] += ge[u][i] * w2v[u];
#pragma unroll
        for (int d = 1; d <= 8; d <<= 1)
#pragma unroll
            for (int i = 0; i < 4; ++i) part[i] += __shfl_xor(part[i], d, 64);
        if (nl == 0) {
            float bb = b2[0];
#pragma unroll
            for (int i = 0; i < 4; ++i) {
                int c = gc0 + qd * 4 + i;
                out[c] = (part[i] + bb) * vld[c];
            }
        }
    }
}

extern "C" void kernel_launch(void* const* d_in, const int* in_sizes, int n_in,
                              void* d_out, int out_size, void* d_ws, size_t ws_size,
                              hipStream_t stream) {
    const float* x         = (const float*)d_in[0];
    const int*   mask      = (const int*)d_in[1];
    const float* query     = (const float*)d_in[2];
    const float* in_proj_w = (const float*)d_in[3];
    const float* in_proj_b = (const float*)d_in[4];
    const float* out_w     = (const float*)d_in[5];
    const float* out_b     = (const float*)d_in[6];
    const float* ln_g      = (const float*)d_in[7];
    const float* ln_b      = (const float*)d_in[8];
    const float* w1        = (const float*)d_in[9];
    const float* b1        = (const float*)d_in[10];
    const float* w2        = (const float*)d_in[11];
    const float* b2        = (const float*)d_in[12];
    float* out = (float*)d_out;
    unsigned char* ws = (unsigned char*)d_ws;

    const int BN = out_size;   // 32768

    setup_all<<<128, NTHREADS, 0, stream>>>(query, in_proj_w, in_proj_b, out_w, w1, ws);

    // slice xbar to fit d_ws (deterministic for fixed ws_size -> graph-safe)
    size_t cap_bytes = ws_size > (size_t)XB_OFF ? ws_size - (size_t)XB_OFF : 0;
    int cap = (int)(cap_bytes / (size_t)(EE * HH * 2));   // chunks that fit
    int slice = (cap >= BN) ? BN : (cap / 64) * 64;
    if (slice < 64) slice = 64;
    if (slice > BN) slice = BN;

    for (int sbase = 0; sbase < BN; sbase += slice) {
        int sc = BN - sbase < slice ? BN - sbase : slice;
        k1_attn<<<sc / 8, NTHREADS, 0, stream>>>(x, mask, ws, sbase);
        k2_head<<<sc / 64, NTHREADS, 0, stream>>>(in_proj_b, out_b, ln_g, ln_b,
                                                  b1, w2, b2, ws, sbase, out);
    }
}